// Round 9
// baseline (322.163 us; speedup 1.0000x reference)
//
#include <hip/hip_runtime.h>

#define B_ 32
#define N_ 4
#define D_ 128
#define M_ 32768
#define K_ 1024

#define IDX_OFF 16777216
#define LOSS_OFF 16908288
#define PERP_OFF 16908292

// ws float-index layout
#define WS_LOSS 0          // 4 floats
#define WS_TICKET 4        // 4 ints (zeroed)
#define WS_CNT 1024        // 4*1024 floats
#define WS_ENORM 8192      // 4*1024 floats (biased: 384 - 0.5*||e||^2)
#define WS_BPACK_F 16384   // packed fp16 codebook: 4 layers * 256KB = 1MB
#define BPACK_LAYER_US 131072
#define WS_EN2D 278528     // 4096 doubles (exact fp64 ||e||^2)

#define SBIAS 384.0f
#define MARGIN 0.04f

typedef _Float16 f16x8 __attribute__((ext_vector_type(8)));
typedef float f32x4 __attribute__((ext_vector_type(4)));

union FragH {
  f16x8 v;
  _Float16 h[8];
  ushort u16[8];
  uint4 q;
};

__device__ __forceinline__ void gload_lds16(const void* g, void* l) {
  __builtin_amdgcn_global_load_lds(
      (const __attribute__((address_space(1))) unsigned int*)g,
      (__attribute__((address_space(3))) unsigned int*)l, 16, 0, 0);
}

// --- prep: pack codebook (fragment order, fp16) + enorm(+fp64) + zero accum ---
__global__ void vq_pack(const float* __restrict__ cb, float* __restrict__ ws) {
  int blk = blockIdx.x, tid = threadIdx.x;
  if (blk < 256) {
    int n = blk >> 6, tile = blk & 63;
    int s = tid >> 6, lane = tid & 63;
    int code = tile * 16 + (lane & 15);
    int dbase = s * 32 + ((lane >> 4) << 3);
    const float* src = cb + ((size_t)(n * K_ + code)) * D_ + dbase;
    float4 v0 = *(const float4*)src;
    float4 v1 = *(const float4*)(src + 4);
    float v[8] = {v0.x, v0.y, v0.z, v0.w, v1.x, v1.y, v1.z, v1.w};
    FragH f;
#pragma unroll
    for (int j = 0; j < 8; ++j) f.h[j] = (_Float16)v[j];  // RNE
    ushort* base = (ushort*)(ws + WS_BPACK_F) + (size_t)n * BPACK_LAYER_US +
                   (size_t)(tile * 4 + s) * 512 + lane * 8;
    *(uint4*)base = f.q;
  } else if (blk < 512) {
    // enorm: 16 codes per block (4 per wave), fp64-exact sum of squares
    int lane = tid & 63, w = tid >> 6;
    int kg0 = (blk - 256) * 16 + w * 4;
#pragma unroll 1
    for (int cc = 0; cc < 4; ++cc) {
      int kg = kg0 + cc;  // 0..4095 global code id (n*1024 + k)
      const float2* row = (const float2*)(cb + (size_t)kg * D_);
      float2 v = row[lane];
      double sd = (double)v.x * (double)v.x + (double)v.y * (double)v.y;
#pragma unroll
      for (int off = 32; off; off >>= 1) sd += __shfl_down(sd, off, 64);
      if (lane == 0) {
        ws[WS_ENORM + kg] = SBIAS - 0.5f * (float)sd;
        ((double*)(ws + WS_EN2D))[kg] = sd;
      }
    }
  } else {
    // zero loss + tickets + histogram
#pragma unroll
    for (int i = 0; i < 20; ++i) ws[i * 256 + tid] = 0.f;
  }
}

// --- main: 1024 blocks x 128 rows, 32 rows/wave via 2 A-sets ---
__global__ __launch_bounds__(256, 4) void vq_main(const float* __restrict__ x,
                                                  const float* __restrict__ cb,
                                                  float* __restrict__ ws,
                                                  float* __restrict__ out) {
  __shared__ alignas(16) char Lds[34848];  // 32KB staging dbuf + ~2KB persistent
  const int tid = threadIdx.x;
  const int bid = blockIdx.x;
  const int n = bid >> 8;          // 4 layers x 256 m-tiles of 128 rows
  const int mblk = bid & 255;
  const int b = mblk >> 3;
  const int hw0 = (mblk & 7) << 7;

  const int lane = tid & 63, w = tid >> 6;
  const int quad = lane >> 4, l15 = lane & 15;

  const float* xbase = x + (size_t)((b * 4 + n) * 128) * 1024 + hw0;
  const float* cbn = cb + (size_t)n * K_ * D_;
  const float* enB = ws + WS_ENORM + n * K_;
  const ushort* bpack_n = (ushort*)(ws + WS_BPACK_F) + (size_t)n * BPACK_LAYER_US;

  // persistent LDS region (beyond all overlays, which use [0, 32768))
  int* sIdx = (int*)(Lds + 32768);      // [128]
  float* dist = (float*)(Lds + 33280);  // [128]
  float* xn = (float*)(Lds + 33792);    // [128]  ||x||^2
  int* list = (int*)(Lds + 34304);      // [128]
  int* lcnt = (int*)(Lds + 34816);      // [1]
  float* red = (float*)(Lds + 34824);   // [4]

  if (tid == 0) *lcnt = 0;

  const uint4* gsrc = (const uint4*)bpack_n;  // 16384 uint4/layer
  uint4* Bsm4 = (uint4*)Lds;

  // prologue: stage chunk 0 FIRST so its latency hides under the long x-load
#pragma unroll
  for (int i = 0; i < 4; ++i)
    gload_lds16(gsrc + i * 256 + w * 64 + lane, Bsm4 + i * 256 + w * 64);

  // ---- A fragments in registers: 32 rows/wave, 2 sets of 16; + ||x||^2 ----
  f16x8 ah[2][4];
#pragma unroll
  for (int set = 0; set < 2; ++set) {
    const int hwl = w * 32 + set * 16 + l15;
    float xs = 0.f;
#pragma unroll
    for (int s = 0; s < 4; ++s) {
      const int dbase = s * 32 + quad * 8;
      FragH fh;
#pragma unroll
      for (int j = 0; j < 8; ++j) {
        float v = xbase[(size_t)(dbase + j) * 1024 + hwl];
        xs = fmaf(v, v, xs);
        fh.h[j] = (_Float16)v;  // RNE
      }
      ah[set][s] = fh.v;
    }
    xs += __shfl_xor(xs, 16, 64);
    xs += __shfl_xor(xs, 32, 64);
    if (quad == 0) xn[w * 32 + set * 16 + l15] = xs;
  }

  float best[8], best2[8];
#pragma unroll
  for (int i = 0; i < 8; ++i) { best[i] = 0.f; best2[i] = 0.f; }

#pragma unroll 1
  for (int c = 0; c < 16; ++c) {
    __syncthreads();  // publishes stage(c)
    if (c < 15) {
      const uint4* src = gsrc + (c + 1) * 1024;
      uint4* dst = Bsm4 + ((c + 1) & 1) * 1024;
#pragma unroll
      for (int i = 0; i < 4; ++i)
        gload_lds16(src + i * 256 + w * 64 + lane, dst + i * 256 + w * 64);
    }
    const ushort* Bcur = (const ushort*)Lds + (c & 1) * 8192;
#pragma unroll
    for (int tin = 0; tin < 4; ++tin) {
      const int t = c * 4 + tin;
      const uint tinv = (uint)(63 - t);
      float en = enB[t * 16 + l15];
      f16x8 bv[4];
#pragma unroll
      for (int s = 0; s < 4; ++s) {
        const ushort* p = Bcur + (tin * 4 + s) * 512 + lane * 8;
        bv[s] = ((const FragH*)p)->v;
      }
      f32x4 acc[2];
#pragma unroll
      for (int set = 0; set < 2; ++set) acc[set] = (f32x4){en, en, en, en};
#pragma unroll
      for (int s = 0; s < 4; ++s) {
#pragma unroll
        for (int set = 0; set < 2; ++set)
          acc[set] = __builtin_amdgcn_mfma_f32_16x16x32_f16(ah[set][s], bv[s], acc[set], 0, 0, 0);
      }
      // packed top-2 on positive floats: key = bits(score+en)&~63 | (63-t)
#pragma unroll
      for (int set = 0; set < 2; ++set) {
#pragma unroll
        for (int r = 0; r < 4; ++r) {
          float key = __uint_as_float((__float_as_uint(acc[set][r]) & 0xFFFFFFC0u) | tinv);
          float ob = best[set * 4 + r];
          best[set * 4 + r] = fmaxf(key, ob);
          best2[set * 4 + r] = __builtin_amdgcn_fmed3f(key, ob, best2[set * 4 + r]);
        }
      }
    }
  }
  __syncthreads();  // staging buffers dead; overlay

  uint* sS = (uint*)Lds;             // [128][17] = 8704 B
  uint* sS2 = (uint*)(Lds + 8704);   // [128][17]
#pragma unroll
  for (int set = 0; set < 2; ++set) {
#pragma unroll
    for (int r = 0; r < 4; ++r) {
      int m = w * 32 + set * 16 + quad * 4 + r;
      sS[m * 17 + l15] = __float_as_uint(best[set * 4 + r]);
      sS2[m * 17 + l15] = __float_as_uint(best2[set * 4 + r]);
    }
  }
  __syncthreads();

  // per-row reduce (one row per thread, tid<128) + dist^2 from score
  if (tid < 128) {
    const int m = tid;
    uint g1 = 0, g2 = 0;
    int gi = 0;
#pragma unroll 4
    for (int li = 0; li < 16; ++li) {
      uint key = sS[m * 17 + li];
      uint sb = key >> 6;
      int kk = (int)(63u - (key & 63u)) * 16 + li;
      if (sb > g1) { g2 = g1; g1 = sb; gi = kk; }
      else {
        if (sb == g1 && kk < gi) gi = kk;
        if (sb > g2) g2 = sb;
      }
      uint sb2 = sS2[m * 17 + li] >> 6;
      if (sb2 > g2) g2 = sb2;
    }
    sIdx[m] = gi;
    float s1f = __uint_as_float(g1 << 6);
    dist[m] = xn[m] - 2.0f * (s1f - SBIAS);  // ||x||^2 - 2*score
    float gap = s1f - __uint_as_float(g2 << 6);
    if (gap < MARGIN) {
      int pos = atomicAdd(lcnt, 1);
      list[pos] = m;
    }
  }
  __syncthreads();

  // ---- fp64 refine (dot form): one coalesced codebook sweep per <=4 rows ----
  const int cnt = *lcnt;
  if (cnt > 0) {
    float* xrs = (float*)Lds;              // [4][128] = 2 KB
    double* dred = (double*)(Lds + 2048);  // [4][32] = 1 KB
    int* kred = (int*)(Lds + 3072);        // [4][32] = 512 B
    const double* en2 = (const double*)(ws + WS_EN2D) + n * K_;
    const int g = tid >> 3, h = tid & 7;   // g: code group 0..31, h: dim slice
    for (int g0 = 0; g0 < cnt; g0 += 4) {
      const int R = (cnt - g0 < 4) ? (cnt - g0) : 4;
      for (int e = tid; e < R * 128; e += 256)
        xrs[e] = xbase[(size_t)(e & 127) * 1024 + list[g0 + (e >> 7)]];
      __syncthreads();
      double pbd[4];
      int pbk[4];
#pragma unroll
      for (int r = 0; r < 4; ++r) { pbd[r] = 1e300; pbk[r] = 0; }
#pragma unroll 1
      for (int c = 0; c < 32; ++c) {
        const int k = c * 32 + g;
        const float4* er = (const float4*)(cbn + (size_t)k * D_) + h * 4;
        float4 E0 = er[0], E1 = er[1], E2 = er[2], E3 = er[3];
        double e2 = en2[k];
#pragma unroll
        for (int r = 0; r < 4; ++r) {
          if (r < R) {
            const float4* xp4 = (const float4*)(xrs + r * 128) + h * 4;
            double dot = 0.0;
            float4 xv;
            xv = xp4[0];
            dot = fma((double)xv.x, (double)E0.x, dot); dot = fma((double)xv.y, (double)E0.y, dot);
            dot = fma((double)xv.z, (double)E0.z, dot); dot = fma((double)xv.w, (double)E0.w, dot);
            xv = xp4[1];
            dot = fma((double)xv.x, (double)E1.x, dot); dot = fma((double)xv.y, (double)E1.y, dot);
            dot = fma((double)xv.z, (double)E1.z, dot); dot = fma((double)xv.w, (double)E1.w, dot);
            xv = xp4[2];
            dot = fma((double)xv.x, (double)E2.x, dot); dot = fma((double)xv.y, (double)E2.y, dot);
            dot = fma((double)xv.z, (double)E2.z, dot); dot = fma((double)xv.w, (double)E2.w, dot);
            xv = xp4[3];
            dot = fma((double)xv.x, (double)E3.x, dot); dot = fma((double)xv.y, (double)E3.y, dot);
            dot = fma((double)xv.z, (double)E3.z, dot); dot = fma((double)xv.w, (double)E3.w, dot);
            // reduce over the 8-lane dim-slice group
            dot += __shfl_xor(dot, 1, 64);
            dot += __shfl_xor(dot, 2, 64);
            dot += __shfl_xor(dot, 4, 64);
            double v = e2 - 2.0 * dot;  // d^2 - ||x||^2 (constant shift per row)
            if (v < pbd[r]) { pbd[r] = v; pbk[r] = k; }
          }
        }
      }
      if (h == 0) {
#pragma unroll
        for (int r = 0; r < 4; ++r)
          if (r < R) { dred[r * 32 + g] = pbd[r]; kred[r * 32 + g] = pbk[r]; }
      }
      __syncthreads();
      if (tid < R) {
        double bd = 1e300;
        int bk = 0;
#pragma unroll 4
        for (int g2i = 0; g2i < 32; ++g2i) {
          double d = dred[tid * 32 + g2i];
          int kk = kred[tid * 32 + g2i];
          if (d < bd || (d == bd && kk < bk)) { bd = d; bk = kk; }
        }
        int m = list[g0 + tid];
        sIdx[m] = bk;
        dist[m] = xn[m] + (float)bd;
      }
      __syncthreads();
    }
  }

  // ---- indices + histogram + loss ----
  if (tid < 128) {
    int bi = sIdx[tid];
    out[IDX_OFF + (b * 4 + n) * 1024 + hw0 + tid] = (float)bi;
    atomicAdd(ws + WS_CNT + n * K_ + bi, 1.0f);
  }
  {
    float lp = (tid < 128) ? dist[tid] : 0.f;
#pragma unroll
    for (int off = 32; off; off >>= 1) lp += __shfl_down(lp, off, 64);
    if (lane == 0 && w < 2) atomicAdd(ws + WS_LOSS + n, lp);
  }
  __syncthreads();

  // ---- quantized write via LDS-staged gather, 2 d-halves of 64 ----
  float* Qs = (float*)Lds;  // [64 d][128 m] = 32 KB
  float* out0 = out + (size_t)((b * 4 + n) * 128) * 1024 + hw0;
#pragma unroll 1
  for (int h = 0; h < 2; ++h) {
    const int m = tid & 127, part = tid >> 7;
    const float* src = cbn + (size_t)sIdx[m] * D_ + h * 64 + part * 32;
#pragma unroll
    for (int i = 0; i < 8; ++i) {
      float4 v = ((const float4*)src)[i];
      int dl = part * 32 + i * 4;
      Qs[(dl + 0) * 128 + m] = v.x;
      Qs[(dl + 1) * 128 + m] = v.y;
      Qs[(dl + 2) * 128 + m] = v.z;
      Qs[(dl + 3) * 128 + m] = v.w;
    }
    __syncthreads();
#pragma unroll
    for (int it = 0; it < 8; ++it) {
      int e = it * 256 + tid;
      int m4 = (e & 31) * 4;
      int dl = e >> 5;
      float4 v = *(float4*)(Qs + dl * 128 + m4);
      *(float4*)(out0 + (size_t)(h * 64 + dl) * 1024 + m4) = v;
    }
    __syncthreads();
  }

  // ---- last block of this layer computes loss scale + perplexity ----
  __threadfence();
  if (tid == 0) {
    int tk = atomicAdd((int*)ws + WS_TICKET + n, 1);
    *lcnt = (tk == 255) ? 1 : 0;
  }
  __syncthreads();
  if (*lcnt) {
    float s = 0.f;
    for (int k = tid; k < K_; k += 256) {
      float c = atomicAdd(ws + WS_CNT + n * K_ + k, 0.0f);  // device-scope load
      float p = c * (1.0f / 32768.0f);
      s += p * logf(p + 1e-10f);
    }
#pragma unroll
    for (int off = 32; off; off >>= 1) s += __shfl_down(s, off, 64);
    if ((tid & 63) == 0) red[tid >> 6] = s;
    __syncthreads();
    if (tid == 0) {
      s = red[0] + red[1] + red[2] + red[3];
      out[PERP_OFF + n] = expf(-s);
      float L = atomicAdd(ws + WS_LOSS + n, 0.0f);
      out[LOSS_OFF + n] = 1.25f * L / 4194304.0f;
    }
  }
}

extern "C" void kernel_launch(void* const* d_in, const int* in_sizes, int n_in,
                              void* d_out, int out_size, void* d_ws, size_t ws_size,
                              hipStream_t stream) {
  const float* x = (const float*)d_in[0];
  const float* cb = (const float*)d_in[1];
  float* out = (float*)d_out;
  float* ws = (float*)d_ws;
  vq_pack<<<513, 256, 0, stream>>>(cb, ws);
  vq_main<<<1024, 256, 0, stream>>>(x, cb, ws, out);
}

// Round 12
// 244.905 us; speedup vs baseline: 1.3155x; 1.3155x over previous
//
#include <hip/hip_runtime.h>

#define B_ 32
#define N_ 4
#define D_ 128
#define M_ 32768
#define K_ 1024

#define IDX_OFF 16777216
#define LOSS_OFF 16908288
#define PERP_OFF 16908292

// ws float-index layout
#define WS_LOSS 0          // 4 floats
#define WS_CNT 1024        // 4*1024 floats
#define WS_ENORM 8192      // 4*1024 floats (biased: 384 - 0.5*||e||^2)
#define WS_BPACK_F 16384   // packed fp16 codebook: 4 layers * 256KB = 1MB
#define BPACK_LAYER_US 131072
#define WS_EN2D 278528     // 4096 doubles (exact fp64 ||e||^2)

#define SBIAS 384.0f
#define MARGIN 0.04f

typedef _Float16 f16x8 __attribute__((ext_vector_type(8)));
typedef float f32x4 __attribute__((ext_vector_type(4)));

union FragH {
  f16x8 v;
  _Float16 h[8];
  ushort u16[8];
  uint4 q;
};

__device__ __forceinline__ void gload_lds16(const void* g, void* l) {
  __builtin_amdgcn_global_load_lds(
      (const __attribute__((address_space(1))) unsigned int*)g,
      (__attribute__((address_space(3))) unsigned int*)l, 16, 0, 0);
}

// --- prep: pack codebook (fragment order, fp16) + enorm(+fp64) + zero accum ---
__global__ void vq_pack(const float* __restrict__ cb, float* __restrict__ ws) {
  int blk = blockIdx.x, tid = threadIdx.x;
  if (blk < 256) {
    int n = blk >> 6, tile = blk & 63;
    int s = tid >> 6, lane = tid & 63;
    int code = tile * 16 + (lane & 15);
    int dbase = s * 32 + ((lane >> 4) << 3);
    const float* src = cb + ((size_t)(n * K_ + code)) * D_ + dbase;
    float4 v0 = *(const float4*)src;
    float4 v1 = *(const float4*)(src + 4);
    float v[8] = {v0.x, v0.y, v0.z, v0.w, v1.x, v1.y, v1.z, v1.w};
    FragH f;
#pragma unroll
    for (int j = 0; j < 8; ++j) f.h[j] = (_Float16)v[j];  // RNE
    ushort* base = (ushort*)(ws + WS_BPACK_F) + (size_t)n * BPACK_LAYER_US +
                   (size_t)(tile * 4 + s) * 512 + lane * 8;
    *(uint4*)base = f.q;
  } else if (blk < 512) {
    // enorm: 16 codes per block (4 per wave), fp64-exact sum of squares
    int lane = tid & 63, w = tid >> 6;
    int kg0 = (blk - 256) * 16 + w * 4;
#pragma unroll 1
    for (int cc = 0; cc < 4; ++cc) {
      int kg = kg0 + cc;  // 0..4095 global code id (n*1024 + k)
      const float2* row = (const float2*)(cb + (size_t)kg * D_);
      float2 v = row[lane];
      double sd = (double)v.x * (double)v.x + (double)v.y * (double)v.y;
#pragma unroll
      for (int off = 32; off; off >>= 1) sd += __shfl_down(sd, off, 64);
      if (lane == 0) {
        ws[WS_ENORM + kg] = SBIAS - 0.5f * (float)sd;
        ((double*)(ws + WS_EN2D))[kg] = sd;
      }
    }
  } else {
    // zero loss + histogram
#pragma unroll
    for (int i = 0; i < 20; ++i) ws[i * 256 + tid] = 0.f;
  }
}

// --- main: 1024 blocks x 128 rows, 32 rows/wave via 2 A-sets ---
__global__ __launch_bounds__(256, 4) void vq_main(const float* __restrict__ x,
                                                  const float* __restrict__ cb,
                                                  float* __restrict__ ws,
                                                  float* __restrict__ out) {
  __shared__ alignas(16) char Lds[34832];  // 32KB staging dbuf + ~2KB persistent
  const int tid = threadIdx.x;
  const int bid = blockIdx.x;
  const int n = bid >> 8;          // 4 layers x 256 m-tiles of 128 rows
  const int mblk = bid & 255;
  const int b = mblk >> 3;
  const int hw0 = (mblk & 7) << 7;

  const int lane = tid & 63, w = tid >> 6;
  const int quad = lane >> 4, l15 = lane & 15;

  const float* xbase = x + (size_t)((b * 4 + n) * 128) * 1024 + hw0;
  const float* cbn = cb + (size_t)n * K_ * D_;
  const float* enB = ws + WS_ENORM + n * K_;
  const ushort* bpack_n = (ushort*)(ws + WS_BPACK_F) + (size_t)n * BPACK_LAYER_US;

  // persistent LDS region (beyond all overlays, which use [0, 32768))
  int* sIdx = (int*)(Lds + 32768);      // [128]
  float* dist = (float*)(Lds + 33280);  // [128]
  float* xn = (float*)(Lds + 33792);    // [128]  ||x||^2
  int* list = (int*)(Lds + 34304);      // [128]
  int* lcnt = (int*)(Lds + 34816);      // [1]

  if (tid == 0) *lcnt = 0;

  const uint4* gsrc = (const uint4*)bpack_n;  // 16384 uint4/layer
  uint4* Bsm4 = (uint4*)Lds;

  // prologue: stage chunk 0 FIRST so its latency hides under the long x-load
#pragma unroll
  for (int i = 0; i < 4; ++i)
    gload_lds16(gsrc + i * 256 + w * 64 + lane, Bsm4 + i * 256 + w * 64);

  // ---- A fragments in registers: 32 rows/wave, 2 sets of 16; + ||x||^2 ----
  f16x8 ah[2][4];
#pragma unroll
  for (int set = 0; set < 2; ++set) {
    const int hwl = w * 32 + set * 16 + l15;
    float xs = 0.f;
#pragma unroll
    for (int s = 0; s < 4; ++s) {
      const int dbase = s * 32 + quad * 8;
      FragH fh;
#pragma unroll
      for (int j = 0; j < 8; ++j) {
        float v = xbase[(size_t)(dbase + j) * 1024 + hwl];
        xs = fmaf(v, v, xs);
        fh.h[j] = (_Float16)v;  // RNE
      }
      ah[set][s] = fh.v;
    }
    xs += __shfl_xor(xs, 16, 64);
    xs += __shfl_xor(xs, 32, 64);
    if (quad == 0) xn[w * 32 + set * 16 + l15] = xs;
  }

  float best[8], best2[8];
#pragma unroll
  for (int i = 0; i < 8; ++i) { best[i] = 0.f; best2[i] = 0.f; }

#pragma unroll 1
  for (int c = 0; c < 16; ++c) {
    __syncthreads();  // publishes stage(c)
    if (c < 15) {
      const uint4* src = gsrc + (c + 1) * 1024;
      uint4* dst = Bsm4 + ((c + 1) & 1) * 1024;
#pragma unroll
      for (int i = 0; i < 4; ++i)
        gload_lds16(src + i * 256 + w * 64 + lane, dst + i * 256 + w * 64);
    }
    const ushort* Bcur = (const ushort*)Lds + (c & 1) * 8192;
#pragma unroll
    for (int tin = 0; tin < 4; ++tin) {
      const int t = c * 4 + tin;
      const uint tinv = (uint)(63 - t);
      float en = enB[t * 16 + l15];
      f16x8 bv[4];
#pragma unroll
      for (int s = 0; s < 4; ++s) {
        const ushort* p = Bcur + (tin * 4 + s) * 512 + lane * 8;
        bv[s] = ((const FragH*)p)->v;
      }
      f32x4 acc[2];
#pragma unroll
      for (int set = 0; set < 2; ++set) acc[set] = (f32x4){en, en, en, en};
#pragma unroll
      for (int s = 0; s < 4; ++s) {
#pragma unroll
        for (int set = 0; set < 2; ++set)
          acc[set] = __builtin_amdgcn_mfma_f32_16x16x32_f16(ah[set][s], bv[s], acc[set], 0, 0, 0);
      }
      // packed top-2 on positive floats: key = bits(score+en)&~63 | (63-t)
#pragma unroll
      for (int set = 0; set < 2; ++set) {
#pragma unroll
        for (int r = 0; r < 4; ++r) {
          float key = __uint_as_float((__float_as_uint(acc[set][r]) & 0xFFFFFFC0u) | tinv);
          float ob = best[set * 4 + r];
          best[set * 4 + r] = fmaxf(key, ob);
          best2[set * 4 + r] = __builtin_amdgcn_fmed3f(key, ob, best2[set * 4 + r]);
        }
      }
    }
  }
  __syncthreads();  // staging buffers dead; overlay

  uint* sS = (uint*)Lds;             // [128][17] = 8704 B
  uint* sS2 = (uint*)(Lds + 8704);   // [128][17]
#pragma unroll
  for (int set = 0; set < 2; ++set) {
#pragma unroll
    for (int r = 0; r < 4; ++r) {
      int m = w * 32 + set * 16 + quad * 4 + r;
      sS[m * 17 + l15] = __float_as_uint(best[set * 4 + r]);
      sS2[m * 17 + l15] = __float_as_uint(best2[set * 4 + r]);
    }
  }
  __syncthreads();

  // per-row reduce (one row per thread, tid<128) + dist^2 from score
  if (tid < 128) {
    const int m = tid;
    uint g1 = 0, g2 = 0;
    int gi = 0;
#pragma unroll 4
    for (int li = 0; li < 16; ++li) {
      uint key = sS[m * 17 + li];
      uint sb = key >> 6;
      int kk = (int)(63u - (key & 63u)) * 16 + li;
      if (sb > g1) { g2 = g1; g1 = sb; gi = kk; }
      else {
        if (sb == g1 && kk < gi) gi = kk;
        if (sb > g2) g2 = sb;
      }
      uint sb2 = sS2[m * 17 + li] >> 6;
      if (sb2 > g2) g2 = sb2;
    }
    sIdx[m] = gi;
    float s1f = __uint_as_float(g1 << 6);
    dist[m] = xn[m] - 2.0f * (s1f - SBIAS);  // ||x||^2 - 2*score
    float gap = s1f - __uint_as_float(g2 << 6);
    if (gap < MARGIN) {
      int pos = atomicAdd(lcnt, 1);
      list[pos] = m;
    }
  }
  __syncthreads();

  // ---- fp64 refine (dot form): one coalesced codebook sweep per <=4 rows ----
  const int cnt = *lcnt;
  if (cnt > 0) {
    float* xrs = (float*)Lds;              // [4][128] = 2 KB
    double* dred = (double*)(Lds + 2048);  // [4][32] = 1 KB
    int* kred = (int*)(Lds + 3072);        // [4][32] = 512 B
    const double* en2 = (const double*)(ws + WS_EN2D) + n * K_;
    const int g = tid >> 3, h = tid & 7;   // g: code group 0..31, h: dim slice
    for (int g0 = 0; g0 < cnt; g0 += 4) {
      const int R = (cnt - g0 < 4) ? (cnt - g0) : 4;
      for (int e = tid; e < R * 128; e += 256)
        xrs[e] = xbase[(size_t)(e & 127) * 1024 + list[g0 + (e >> 7)]];
      __syncthreads();
      double pbd[4];
      int pbk[4];
#pragma unroll
      for (int r = 0; r < 4; ++r) { pbd[r] = 1e300; pbk[r] = 0; }
#pragma unroll 1
      for (int c = 0; c < 32; ++c) {
        const int k = c * 32 + g;
        const float4* er = (const float4*)(cbn + (size_t)k * D_) + h * 4;
        float4 E0 = er[0], E1 = er[1], E2 = er[2], E3 = er[3];
        double e2 = en2[k];
#pragma unroll
        for (int r = 0; r < 4; ++r) {
          if (r < R) {
            const float4* xp4 = (const float4*)(xrs + r * 128) + h * 4;
            double dot = 0.0;
            float4 xv;
            xv = xp4[0];
            dot = fma((double)xv.x, (double)E0.x, dot); dot = fma((double)xv.y, (double)E0.y, dot);
            dot = fma((double)xv.z, (double)E0.z, dot); dot = fma((double)xv.w, (double)E0.w, dot);
            xv = xp4[1];
            dot = fma((double)xv.x, (double)E1.x, dot); dot = fma((double)xv.y, (double)E1.y, dot);
            dot = fma((double)xv.z, (double)E1.z, dot); dot = fma((double)xv.w, (double)E1.w, dot);
            xv = xp4[2];
            dot = fma((double)xv.x, (double)E2.x, dot); dot = fma((double)xv.y, (double)E2.y, dot);
            dot = fma((double)xv.z, (double)E2.z, dot); dot = fma((double)xv.w, (double)E2.w, dot);
            xv = xp4[3];
            dot = fma((double)xv.x, (double)E3.x, dot); dot = fma((double)xv.y, (double)E3.y, dot);
            dot = fma((double)xv.z, (double)E3.z, dot); dot = fma((double)xv.w, (double)E3.w, dot);
            // reduce over the 8-lane dim-slice group
            dot += __shfl_xor(dot, 1, 64);
            dot += __shfl_xor(dot, 2, 64);
            dot += __shfl_xor(dot, 4, 64);
            double v = e2 - 2.0 * dot;  // d^2 - ||x||^2 (constant shift per row)
            if (v < pbd[r]) { pbd[r] = v; pbk[r] = k; }
          }
        }
      }
      if (h == 0) {
#pragma unroll
        for (int r = 0; r < 4; ++r)
          if (r < R) { dred[r * 32 + g] = pbd[r]; kred[r * 32 + g] = pbk[r]; }
      }
      __syncthreads();
      if (tid < R) {
        double bd = 1e300;
        int bk = 0;
#pragma unroll 4
        for (int g2i = 0; g2i < 32; ++g2i) {
          double d = dred[tid * 32 + g2i];
          int kk = kred[tid * 32 + g2i];
          if (d < bd || (d == bd && kk < bk)) { bd = d; bk = kk; }
        }
        int m = list[g0 + tid];
        sIdx[m] = bk;
        dist[m] = xn[m] + (float)bd;
      }
      __syncthreads();
    }
  }

  // ---- indices + histogram + loss ----
  if (tid < 128) {
    int bi = sIdx[tid];
    out[IDX_OFF + (b * 4 + n) * 1024 + hw0 + tid] = (float)bi;
    atomicAdd(ws + WS_CNT + n * K_ + bi, 1.0f);
  }
  {
    float lp = (tid < 128) ? dist[tid] : 0.f;
#pragma unroll
    for (int off = 32; off; off >>= 1) lp += __shfl_down(lp, off, 64);
    if (lane == 0 && w < 2) atomicAdd(ws + WS_LOSS + n, lp);
  }
  __syncthreads();

  // ---- quantized write via LDS-staged gather, 2 d-halves of 64 ----
  float* Qs = (float*)Lds;  // [64 d][128 m] = 32 KB
  float* out0 = out + (size_t)((b * 4 + n) * 128) * 1024 + hw0;
#pragma unroll 1
  for (int h = 0; h < 2; ++h) {
    const int m = tid & 127, part = tid >> 7;
    const float* src = cbn + (size_t)sIdx[m] * D_ + h * 64 + part * 32;
#pragma unroll
    for (int i = 0; i < 8; ++i) {
      float4 v = ((const float4*)src)[i];
      int dl = part * 32 + i * 4;
      Qs[(dl + 0) * 128 + m] = v.x;
      Qs[(dl + 1) * 128 + m] = v.y;
      Qs[(dl + 2) * 128 + m] = v.z;
      Qs[(dl + 3) * 128 + m] = v.w;
    }
    __syncthreads();
#pragma unroll
    for (int it = 0; it < 8; ++it) {
      int e = it * 256 + tid;
      int m4 = (e & 31) * 4;
      int dl = e >> 5;
      float4 v = *(float4*)(Qs + dl * 128 + m4);
      *(float4*)(out0 + (size_t)(h * 64 + dl) * 1024 + m4) = v;
    }
    __syncthreads();
  }
}

// --- finalize: loss scale + perplexity ---
__global__ void vq_finalize(const float* __restrict__ ws, float* __restrict__ out) {
  int n = blockIdx.x;
  int t = threadIdx.x;
  const float* counts = ws + WS_CNT + n * K_;
  float s = 0.f;
  for (int k = t; k < K_; k += 256) {
    float p = counts[k] * (1.0f / 32768.0f);
    s += p * logf(p + 1e-10f);
  }
  __shared__ float red[4];
#pragma unroll
  for (int off = 32; off; off >>= 1) s += __shfl_down(s, off, 64);
  if ((t & 63) == 0) red[t >> 6] = s;
  __syncthreads();
  if (t == 0) {
    s = red[0] + red[1] + red[2] + red[3];
    out[PERP_OFF + n] = expf(-s);
    out[LOSS_OFF + n] = 1.25f * ws[WS_LOSS + n] / 4194304.0f;
  }
}

extern "C" void kernel_launch(void* const* d_in, const int* in_sizes, int n_in,
                              void* d_out, int out_size, void* d_ws, size_t ws_size,
                              hipStream_t stream) {
  const float* x = (const float*)d_in[0];
  const float* cb = (const float*)d_in[1];
  float* out = (float*)d_out;
  float* ws = (float*)d_ws;
  vq_pack<<<513, 256, 0, stream>>>(cb, ws);
  vq_main<<<1024, 256, 0, stream>>>(x, cb, ws, out);
  vq_finalize<<<4, 256, 0, stream>>>(ws, out);
}

// Round 17
// 243.363 us; speedup vs baseline: 1.3238x; 1.0063x over previous
//
#include <hip/hip_runtime.h>

#define B_ 32
#define N_ 4
#define D_ 128
#define M_ 32768
#define K_ 1024

#define IDX_OFF 16777216
#define LOSS_OFF 16908288
#define PERP_OFF 16908292

// ws float-index layout
#define WS_LOSS 0          // 4 floats
#define WS_CNT 1024        // 4*1024 floats
#define WS_ENORM 8192      // 4*1024 floats (biased: 384 - 0.5*||e||^2)
#define WS_BPACK_F 16384   // packed fp16 codebook: 4 layers * 256KB = 1MB
#define BPACK_LAYER_US 131072
#define WS_EN2D 278528     // 4096 doubles (exact fp64 ||e||^2)

#define SBIAS 384.0f
#define MARGIN 0.04f

typedef _Float16 f16x8 __attribute__((ext_vector_type(8)));
typedef float f32x4 __attribute__((ext_vector_type(4)));

union FragH {
  f16x8 v;
  _Float16 h[8];
  ushort u16[8];
  uint4 q;
};

__device__ __forceinline__ void gload_lds16(const void* g, void* l) {
  __builtin_amdgcn_global_load_lds(
      (const __attribute__((address_space(1))) unsigned int*)g,
      (__attribute__((address_space(3))) unsigned int*)l, 16, 0, 0);
}

// --- prep: pack codebook (fragment order, fp16) + enorm(+fp64) + zero accum ---
__global__ void vq_pack(const float* __restrict__ cb, float* __restrict__ ws) {
  int blk = blockIdx.x, tid = threadIdx.x;
  if (blk < 256) {
    int n = blk >> 6, tile = blk & 63;
    int s = tid >> 6, lane = tid & 63;
    int code = tile * 16 + (lane & 15);
    int dbase = s * 32 + ((lane >> 4) << 3);
    const float* src = cb + ((size_t)(n * K_ + code)) * D_ + dbase;
    float4 v0 = *(const float4*)src;
    float4 v1 = *(const float4*)(src + 4);
    float v[8] = {v0.x, v0.y, v0.z, v0.w, v1.x, v1.y, v1.z, v1.w};
    FragH f;
#pragma unroll
    for (int j = 0; j < 8; ++j) f.h[j] = (_Float16)v[j];  // RNE
    ushort* base = (ushort*)(ws + WS_BPACK_F) + (size_t)n * BPACK_LAYER_US +
                   (size_t)(tile * 4 + s) * 512 + lane * 8;
    *(uint4*)base = f.q;
  } else if (blk < 512) {
    // enorm: 16 codes per block (4 per wave), fp64-exact sum of squares
    int lane = tid & 63, w = tid >> 6;
    int kg0 = (blk - 256) * 16 + w * 4;
#pragma unroll 1
    for (int cc = 0; cc < 4; ++cc) {
      int kg = kg0 + cc;  // 0..4095 global code id (n*1024 + k)
      const float2* row = (const float2*)(cb + (size_t)kg * D_);
      float2 v = row[lane];
      double sd = (double)v.x * (double)v.x + (double)v.y * (double)v.y;
#pragma unroll
      for (int off = 32; off; off >>= 1) sd += __shfl_down(sd, off, 64);
      if (lane == 0) {
        ws[WS_ENORM + kg] = SBIAS - 0.5f * (float)sd;
        ((double*)(ws + WS_EN2D))[kg] = sd;
      }
    }
  } else {
    // zero loss + histogram
#pragma unroll
    for (int i = 0; i < 20; ++i) ws[i * 256 + tid] = 0.f;
  }
}

// --- main: 1024 blocks x 128 rows, 32 rows/wave via 2 A-sets ---
__global__ __launch_bounds__(256, 4) void vq_main(const float* __restrict__ x,
                                                  const float* __restrict__ cb,
                                                  float* __restrict__ ws,
                                                  float* __restrict__ out) {
  __shared__ alignas(16) char Lds[34832];  // 32KB staging dbuf + ~2KB persistent
  const int tid = threadIdx.x;
  const int bid = blockIdx.x;
  const int n = bid >> 8;          // 4 layers x 256 m-tiles of 128 rows
  const int mblk = bid & 255;
  const int b = mblk >> 3;
  const int hw0 = (mblk & 7) << 7;

  const int lane = tid & 63, w = tid >> 6;
  const int quad = lane >> 4, l15 = lane & 15;

  const float* xbase = x + (size_t)((b * 4 + n) * 128) * 1024 + hw0;
  const float* cbn = cb + (size_t)n * K_ * D_;
  const float* enB = ws + WS_ENORM + n * K_;
  const ushort* bpack_n = (ushort*)(ws + WS_BPACK_F) + (size_t)n * BPACK_LAYER_US;

  // persistent LDS region (beyond all overlays, which use [0, 32768))
  int* sIdx = (int*)(Lds + 32768);      // [128]
  float* dist = (float*)(Lds + 33280);  // [128]
  float* xn = (float*)(Lds + 33792);    // [128]  ||x||^2
  int* list = (int*)(Lds + 34304);      // [128]
  int* lcnt = (int*)(Lds + 34816);      // [1]

  if (tid == 0) *lcnt = 0;

  const uint4* gsrc = (const uint4*)bpack_n;  // 16384 uint4/layer
  uint4* Bsm4 = (uint4*)Lds;

  // prologue: stage chunk 0 FIRST so its latency hides under the long x-load
#pragma unroll
  for (int i = 0; i < 4; ++i)
    gload_lds16(gsrc + i * 256 + w * 64 + lane, Bsm4 + i * 256 + w * 64);

  // ---- A fragments in registers: 32 rows/wave, 2 sets of 16; + ||x||^2 ----
  f16x8 ah[2][4];
#pragma unroll
  for (int set = 0; set < 2; ++set) {
    const int hwl = w * 32 + set * 16 + l15;
    float xs = 0.f;
#pragma unroll
    for (int s = 0; s < 4; ++s) {
      const int dbase = s * 32 + quad * 8;
      FragH fh;
#pragma unroll
      for (int j = 0; j < 8; ++j) {
        float v = xbase[(size_t)(dbase + j) * 1024 + hwl];
        xs = fmaf(v, v, xs);
        fh.h[j] = (_Float16)v;  // RNE
      }
      ah[set][s] = fh.v;
    }
    xs += __shfl_xor(xs, 16, 64);
    xs += __shfl_xor(xs, 32, 64);
    if (quad == 0) xn[w * 32 + set * 16 + l15] = xs;
  }

  float best[8], best2[8];
#pragma unroll
  for (int i = 0; i < 8; ++i) { best[i] = 0.f; best2[i] = 0.f; }

#pragma unroll 1
  for (int c = 0; c < 16; ++c) {
    __syncthreads();  // publishes stage(c)
    if (c < 15) {
      const uint4* src = gsrc + (c + 1) * 1024;
      uint4* dst = Bsm4 + ((c + 1) & 1) * 1024;
#pragma unroll
      for (int i = 0; i < 4; ++i)
        gload_lds16(src + i * 256 + w * 64 + lane, dst + i * 256 + w * 64);
    }
    const ushort* Bcur = (const ushort*)Lds + (c & 1) * 8192;
#pragma unroll
    for (int tin = 0; tin < 4; ++tin) {
      const int t = c * 4 + tin;
      const uint tinv = (uint)(63 - t);
      float en = enB[t * 16 + l15];
      f16x8 bv[4];
#pragma unroll
      for (int s = 0; s < 4; ++s) {
        const ushort* p = Bcur + (tin * 4 + s) * 512 + lane * 8;
        bv[s] = ((const FragH*)p)->v;
      }
      f32x4 acc[2];
#pragma unroll
      for (int set = 0; set < 2; ++set) acc[set] = (f32x4){en, en, en, en};
#pragma unroll
      for (int s = 0; s < 4; ++s) {
#pragma unroll
        for (int set = 0; set < 2; ++set)
          acc[set] = __builtin_amdgcn_mfma_f32_16x16x32_f16(ah[set][s], bv[s], acc[set], 0, 0, 0);
      }
      // packed top-2 on positive floats: key = bits(score+en)&~63 | (63-t)
#pragma unroll
      for (int set = 0; set < 2; ++set) {
#pragma unroll
        for (int r = 0; r < 4; ++r) {
          float key = __uint_as_float((__float_as_uint(acc[set][r]) & 0xFFFFFFC0u) | tinv);
          float ob = best[set * 4 + r];
          best[set * 4 + r] = fmaxf(key, ob);
          best2[set * 4 + r] = __builtin_amdgcn_fmed3f(key, ob, best2[set * 4 + r]);
        }
      }
    }
  }
  __syncthreads();  // staging buffers dead; overlay

  uint* sS = (uint*)Lds;             // [128][17] = 8704 B
  uint* sS2 = (uint*)(Lds + 8704);   // [128][17]
#pragma unroll
  for (int set = 0; set < 2; ++set) {
#pragma unroll
    for (int r = 0; r < 4; ++r) {
      int m = w * 32 + set * 16 + quad * 4 + r;
      sS[m * 17 + l15] = __float_as_uint(best[set * 4 + r]);
      sS2[m * 17 + l15] = __float_as_uint(best2[set * 4 + r]);
    }
  }
  __syncthreads();

  // per-row reduce (one row per thread, tid<128) + dist^2 from score
  if (tid < 128) {
    const int m = tid;
    uint g1 = 0, g2 = 0;
    int gi = 0;
#pragma unroll 4
    for (int li = 0; li < 16; ++li) {
      uint key = sS[m * 17 + li];
      uint sb = key >> 6;
      int kk = (int)(63u - (key & 63u)) * 16 + li;
      if (sb > g1) { g2 = g1; g1 = sb; gi = kk; }
      else {
        if (sb == g1 && kk < gi) gi = kk;
        if (sb > g2) g2 = sb;
      }
      uint sb2 = sS2[m * 17 + li] >> 6;
      if (sb2 > g2) g2 = sb2;
    }
    sIdx[m] = gi;
    float s1f = __uint_as_float(g1 << 6);
    dist[m] = xn[m] - 2.0f * (s1f - SBIAS);  // ||x||^2 - 2*score
    float gap = s1f - __uint_as_float(g2 << 6);
    if (gap < MARGIN) {
      int pos = atomicAdd(lcnt, 1);
      list[pos] = m;
    }
  }
  __syncthreads();

  // ---- fp64 refine (dot form): one coalesced codebook sweep per <=4 rows ----
  const int cnt = *lcnt;
  if (cnt > 0) {
    float* xrs = (float*)Lds;              // [4][128] = 2 KB
    double* dred = (double*)(Lds + 2048);  // [4][32] = 1 KB
    int* kred = (int*)(Lds + 3072);        // [4][32] = 512 B
    const double* en2 = (const double*)(ws + WS_EN2D) + n * K_;
    const int g = tid >> 3, h = tid & 7;   // g: code group 0..31, h: dim slice
    for (int g0 = 0; g0 < cnt; g0 += 4) {
      const int R = (cnt - g0 < 4) ? (cnt - g0) : 4;
      for (int e = tid; e < R * 128; e += 256)
        xrs[e] = xbase[(size_t)(e & 127) * 1024 + list[g0 + (e >> 7)]];
      __syncthreads();
      double pbd[4];
      int pbk[4];
#pragma unroll
      for (int r = 0; r < 4; ++r) { pbd[r] = 1e300; pbk[r] = 0; }
#pragma unroll 1
      for (int c = 0; c < 32; ++c) {
        const int k = c * 32 + g;
        const float4* er = (const float4*)(cbn + (size_t)k * D_) + h * 4;
        float4 E0 = er[0], E1 = er[1], E2 = er[2], E3 = er[3];
        double e2 = en2[k];
#pragma unroll
        for (int r = 0; r < 4; ++r) {
          if (r < R) {
            const float4* xp4 = (const float4*)(xrs + r * 128) + h * 4;
            double dot = 0.0;
            float4 xv;
            xv = xp4[0];
            dot = fma((double)xv.x, (double)E0.x, dot); dot = fma((double)xv.y, (double)E0.y, dot);
            dot = fma((double)xv.z, (double)E0.z, dot); dot = fma((double)xv.w, (double)E0.w, dot);
            xv = xp4[1];
            dot = fma((double)xv.x, (double)E1.x, dot); dot = fma((double)xv.y, (double)E1.y, dot);
            dot = fma((double)xv.z, (double)E1.z, dot); dot = fma((double)xv.w, (double)E1.w, dot);
            xv = xp4[2];
            dot = fma((double)xv.x, (double)E2.x, dot); dot = fma((double)xv.y, (double)E2.y, dot);
            dot = fma((double)xv.z, (double)E2.z, dot); dot = fma((double)xv.w, (double)E2.w, dot);
            xv = xp4[3];
            dot = fma((double)xv.x, (double)E3.x, dot); dot = fma((double)xv.y, (double)E3.y, dot);
            dot = fma((double)xv.z, (double)E3.z, dot); dot = fma((double)xv.w, (double)E3.w, dot);
            // reduce over the 8-lane dim-slice group
            dot += __shfl_xor(dot, 1, 64);
            dot += __shfl_xor(dot, 2, 64);
            dot += __shfl_xor(dot, 4, 64);
            double v = e2 - 2.0 * dot;  // d^2 - ||x||^2 (constant shift per row)
            if (v < pbd[r]) { pbd[r] = v; pbk[r] = k; }
          }
        }
      }
      if (h == 0) {
#pragma unroll
        for (int r = 0; r < 4; ++r)
          if (r < R) { dred[r * 32 + g] = pbd[r]; kred[r * 32 + g] = pbk[r]; }
      }
      __syncthreads();
      if (tid < R) {
        double bd = 1e300;
        int bk = 0;
#pragma unroll 4
        for (int g2i = 0; g2i < 32; ++g2i) {
          double d = dred[tid * 32 + g2i];
          int kk = kred[tid * 32 + g2i];
          if (d < bd || (d == bd && kk < bk)) { bd = d; bk = kk; }
        }
        int m = list[g0 + tid];
        sIdx[m] = bk;
        dist[m] = xn[m] + (float)bd;
      }
      __syncthreads();
    }
  }

  // ---- indices + histogram + loss ----
  if (tid < 128) {
    int bi = sIdx[tid];
    out[IDX_OFF + (b * 4 + n) * 1024 + hw0 + tid] = (float)bi;
    atomicAdd(ws + WS_CNT + n * K_ + bi, 1.0f);
  }
  {
    float lp = (tid < 128) ? dist[tid] : 0.f;
#pragma unroll
    for (int off = 32; off; off >>= 1) lp += __shfl_down(lp, off, 64);
    if (lane == 0 && w < 2) atomicAdd(ws + WS_LOSS + n, lp);
  }
  __syncthreads();

  // ---- quantized write via LDS-staged gather, 2 d-halves of 64 ----
  float* Qs = (float*)Lds;  // [64 d][128 m] = 32 KB
  float* out0 = out + (size_t)((b * 4 + n) * 128) * 1024 + hw0;
#pragma unroll 1
  for (int h = 0; h < 2; ++h) {
    const int m = tid & 127, part = tid >> 7;
    const float* src = cbn + (size_t)sIdx[m] * D_ + h * 64 + part * 32;
#pragma unroll
    for (int i = 0; i < 8; ++i) {
      float4 v = ((const float4*)src)[i];
      int dl = part * 32 + i * 4;
      Qs[(dl + 0) * 128 + m] = v.x;
      Qs[(dl + 1) * 128 + m] = v.y;
      Qs[(dl + 2) * 128 + m] = v.z;
      Qs[(dl + 3) * 128 + m] = v.w;
    }
    __syncthreads();
#pragma unroll
    for (int it = 0; it < 8; ++it) {
      int e = it * 256 + tid;
      int m4 = (e & 31) * 4;
      int dl = e >> 5;
      float4 v = *(float4*)(Qs + dl * 128 + m4);
      *(float4*)(out0 + (size_t)(h * 64 + dl) * 1024 + m4) = v;
    }
    __syncthreads();
  }
}

// --- finalize: loss scale + perplexity ---
__global__ void vq_finalize(const float* __restrict__ ws, float* __restrict__ out) {
  int n = blockIdx.x;
  int t = threadIdx.x;
  const float* counts = ws + WS_CNT + n * K_;
  float s = 0.f;
  for (int k = t; k < K_; k += 256) {
    float p = counts[k] * (1.0f / 32768.0f);
    s += p * logf(p + 1e-10f);
  }
  __shared__ float red[4];
#pragma unroll
  for (int off = 32; off; off >>= 1) s += __shfl_down(s, off, 64);
  if ((t & 63) == 0) red[t >> 6] = s;
  __syncthreads();
  if (t == 0) {
    s = red[0] + red[1] + red[2] + red[3];
    out[PERP_OFF + n] = expf(-s);
    out[LOSS_OFF + n] = 1.25f * ws[WS_LOSS + n] / 4194304.0f;
  }
}

extern "C" void kernel_launch(void* const* d_in, const int* in_sizes, int n_in,
                              void* d_out, int out_size, void* d_ws, size_t ws_size,
                              hipStream_t stream) {
  const float* x = (const float*)d_in[0];
  const float* cb = (const float*)d_in[1];
  float* out = (float*)d_out;
  float* ws = (float*)d_ws;
  vq_pack<<<513, 256, 0, stream>>>(cb, ws);
  vq_main<<<1024, 256, 0, stream>>>(x, cb, ws, out);
  vq_finalize<<<4, 256, 0, stream>>>(ws, out);
}